// Round 6
// baseline (386.045 us; speedup 1.0000x reference)
//
#include <hip/hip_runtime.h>
#include <hip/hip_bf16.h>
#include <hip/hip_fp16.h>
#include <math.h>

#define IN_DIM 128
#define OUT_DIM 128
#define HEADS 4
#define HEAD_DIM 32
#define NREL 3
#define NEG_SLOPE 0.2f

#define CHUNK 16384         // edges per partition chunk
#define BUCK_SHIFT 8
#define DPB 256             // dsts per bucket
#define KPB 768             // keys per bucket (DPB * NREL)
// assumes N <= 65536 (src fits 16 bits in packed words)

typedef __attribute__((ext_vector_type(8))) short short8;
typedef __attribute__((ext_vector_type(4))) float f32x4;
typedef unsigned short u16;

static __device__ __forceinline__ float leaky(float x){ return fmaxf(x, NEG_SLOPE*x); }
static __device__ __forceinline__ unsigned bf16rn(float x){
  unsigned b = __float_as_uint(x);
  b += 0x7FFF + ((b>>16)&1u);
  return b>>16;
}
static __device__ __forceinline__ unsigned h2pack(float a, float b){
  union { __half h[2]; unsigned u; } p;
  p.h[0] = __float2half_rn(a); p.h[1] = __float2half_rn(b);
  return p.u;
}

// --- relation softmax + mixed bias ---
__global__ void k_prep(const float* __restrict__ rw, const float* __restrict__ bias,
                       float* __restrict__ smw, float* __restrict__ biasMix){
  int t = threadIdx.x;
  float m = fmaxf(rw[0], fmaxf(rw[1], rw[2]));
  float e0=__expf(rw[0]-m), e1=__expf(rw[1]-m), e2=__expf(rw[2]-m);
  float inv = 1.f/(e0+e1+e2);
  if (t < 3) smw[t] = (t==0?e0:(t==1?e1:e2))*inv;
  if (t < 128)
    biasMix[t] = inv*(e0*bias[t] + e1*bias[OUT_DIM+t] + e2*bias[2*OUT_DIM+t]);
}

// --- x -> bf16 once ---
__global__ __launch_bounds__(256) void k_xq(const float* __restrict__ x,
                                            unsigned* __restrict__ xq, int n8){
  int i = blockIdx.x*256 + threadIdx.x;
  if (i >= n8) return;
  const float4* xp = (const float4*)x + (size_t)i*2;
  float4 v0 = xp[0], v1 = xp[1];
  uint4 o;
  o.x = bf16rn(v0.x) | (bf16rn(v0.y)<<16);
  o.y = bf16rn(v0.z) | (bf16rn(v0.w)<<16);
  o.z = bf16rn(v1.x) | (bf16rn(v1.y)<<16);
  o.w = bf16rn(v1.z) | (bf16rn(v1.w)<<16);
  ((uint4*)xq)[i] = o;
}

// --- build WTall[r][144][128] bf16: cols 0..127 = W^T, 128..135 = (W@att)^T, 136..143 = 0 ---
__global__ void k_wprep(const float* __restrict__ W, const float* __restrict__ att_s,
                        const float* __restrict__ att_d, u16* __restrict__ WTall){
  const int r = blockIdx.x;
  const int t = threadIdx.x;
  const float* Wr = W + (size_t)r*IN_DIM*OUT_DIM;
  u16* WT = WTall + (size_t)r*144*128;
  for (int i=t; i<128*128; i+=256){
    int k = i>>7, col = i&127;
    WT[col*128 + k] = (u16)bf16rn(Wr[i]);
  }
  if (t < 128){
    int k = t;
    for (int h=0; h<4; h++){
      float ss=0.f, sd=0.f;
      for (int c=0; c<32; c++){
        float w = Wr[k*128 + h*32 + c];
        ss = fmaf(w, att_s[(r*4+h)*32+c], ss);
        sd = fmaf(w, att_d[(r*4+h)*32+c], sd);
      }
      WT[(128+h)*128 + k] = (u16)bf16rn(ss);
      WT[(132+h)*128 + k] = (u16)bf16rn(sd);
    }
  }
  for (int i=t; i<8*128; i+=256) WT[136*128 + i] = 0;
}

// --- MFMA GEMM: h = x@W + fused a_s/a_d; h stored channel-sharded: hq2[cg][r][node][8u32] ---
__global__ __launch_bounds__(256) void k_gemm(
    const unsigned* __restrict__ xq, const u16* __restrict__ WTall,
    unsigned* __restrict__ hq2, float* __restrict__ as_, float* __restrict__ ad_, int N){
  const int r = blockIdx.y;
  const int w = threadIdx.x >> 6;
  const int l = threadIdx.x & 63;
  const int row0 = blockIdx.x*128 + w*32;
  const int lg = l >> 4;
  const int lc = l & 15;

  const u16* WT = WTall + (size_t)r*144*128;
  const u16* xh = (const u16*)xq;

  f32x4 acc[2][9];
  #pragma unroll
  for (int rf=0; rf<2; rf++)
    #pragma unroll
    for (int cf=0; cf<9; cf++) acc[rf][cf] = (f32x4){0.f,0.f,0.f,0.f};

  for (int ks=0; ks<4; ks++){
    const int k0 = ks*32 + lg*8;
    short8 a[2];
    #pragma unroll
    for (int rf=0; rf<2; rf++){
      int row = row0 + rf*16 + lc;
      if (row < N) a[rf] = *(const short8*)(xh + (size_t)row*IN_DIM + k0);
      else         a[rf] = (short8){0,0,0,0,0,0,0,0};
    }
    #pragma unroll
    for (int cf=0; cf<9; cf++){
      short8 b = *(const short8*)(WT + (size_t)(cf*16 + lc)*128 + k0);
      #pragma unroll
      for (int rf=0; rf<2; rf++)
        acc[rf][cf] = __builtin_amdgcn_mfma_f32_16x16x32_bf16(a[rf], b, acc[rf][cf], 0, 0, 0);
    }
  }

  #pragma unroll
  for (int rf=0; rf<2; rf++){
    #pragma unroll
    for (int j=0; j<4; j++){
      int row = row0 + rf*16 + lg*4 + j;
      bool ok = (row < N);
      size_t nidx = (size_t)r*N + row;
      #pragma unroll
      for (int cf=0; cf<8; cf++){
        float v = acc[rf][cf][j];
        float pv = __shfl_xor(v, 1);
        if (ok && !(l&1))
          hq2[((size_t)(cf*NREL + r)*N + row)*8 + (lc>>1)] = bf16rn(v) | (bf16rn(pv)<<16);
      }
      float av = acc[rf][8][j];
      if (ok && lc < 4)       as_[nidx*4 + lc]     = av;
      else if (ok && lc < 8)  ad_[nidx*4 + (lc-4)] = av;
    }
  }
}

// --- pass 1: per-chunk histogram over dst buckets ---
__global__ __launch_bounds__(256) void k_hist(const int* __restrict__ ei,
                       int* __restrict__ histG, int E, int NCHUNK, int NBUCK){
  __shared__ int h[256];
  const int c = blockIdx.x, t = threadIdx.x;
  h[t] = 0; __syncthreads();
  const int* dstp = ei + E;
  const int base = c*CHUNK;
  #pragma unroll 4
  for (int it=0; it<CHUNK/256; ++it){
    int e = base + it*256 + t;
    if (e < E) atomicAdd(&h[dstp[e]>>BUCK_SHIFT], 1);
  }
  __syncthreads();
  if (t < NBUCK) histG[t*NCHUNK + c] = h[t];
}

// --- pass 2: exclusive scan of histG, in place; one block ---
__global__ __launch_bounds__(256) void k_scanH(int* __restrict__ histG, int T){
  __shared__ int ps[256];
  const int t = threadIdx.x;
  const int L = (T + 255)/256;
  const int base = t*L;
  int sum = 0;
  for (int i=0;i<L;i++){ int idx=base+i; if(idx<T) sum += histG[idx]; }
  ps[t] = sum; __syncthreads();
  int x = sum;
  for (int off=1; off<256; off<<=1){
    int y = (t>=off)?ps[t-off]:0; __syncthreads();
    x += y; ps[t] = x; __syncthreads();
  }
  int run = x - sum;
  for (int i=0;i<L;i++){
    int idx=base+i;
    if (idx<T){ int v = histG[idx]; histG[idx] = run; run += v; }
  }
}

// --- pass 3: partition edges into buckets; payload (src<<10 | rel<<8 | dstLocal) ---
__global__ __launch_bounds__(256) void k_part(const int* __restrict__ et, const int* __restrict__ ei,
                       const int* __restrict__ histG, unsigned* __restrict__ payload,
                       int E, int NCHUNK, int NBUCK){
  __shared__ int cur[256];
  const int c = blockIdx.x, t = threadIdx.x;
  if (t < NBUCK) cur[t] = histG[t*NCHUNK + c];
  __syncthreads();
  const int* dstp = ei + E;
  const int base = c*CHUNK;
  #pragma unroll 4
  for (int it=0; it<CHUNK/256; ++it){
    int e = base + it*256 + t;
    if (e < E){
      int d = dstp[e];
      int s = ei[e];
      int r = et[e];
      int b = d >> BUCK_SHIFT;
      int pos = atomicAdd(&cur[b], 1);
      payload[pos] = (unsigned)((d & (DPB-1)) | (r<<8) | (s<<10));
    }
  }
}

// --- pass 4: per-bucket CSR with self-loop slots, normalized fp16 alpha (smw folded) ---
__global__ __launch_bounds__(256) void k_csr(const unsigned* __restrict__ payload,
                     const int* __restrict__ histG, const float* __restrict__ as_,
                     const float* __restrict__ ad_, const float* __restrict__ smw,
                     int* __restrict__ offs, unsigned* __restrict__ ssrc2,
                     uint2* __restrict__ alpha, int E, int N, int NCHUNK, int NBUCK){
  __shared__ int cntA[KPB];
  __shared__ int cur[KPB];
  __shared__ float den[KPB*4];
  __shared__ int ps[256];
  const int b = blockIdx.x, t = threadIdx.x;
  const int bs = histG[b*NCHUNK];
  const int be = (b+1 < NBUCK) ? histG[(b+1)*NCHUNK] : E;
  const int outbase = bs + 3*b*DPB;

  for (int k=t; k<KPB; k+=256) cntA[k] = 0;
  for (int k=t; k<KPB*4; k+=256) den[k] = 0.f;
  __syncthreads();
  for (int i=bs+t; i<be; i+=256){
    unsigned p = payload[i];
    atomicAdd(&cntA[(int)(p&255u)*NREL + (int)((p>>8)&3u)], 1);
  }
  __syncthreads();
  const int dst = b*DPB + t;
  const int hs = (dst < N) ? 1 : 0;
  int c0 = cntA[3*t]   + hs;
  int c1 = cntA[3*t+1] + hs;
  int c2 = cntA[3*t+2] + hs;
  int sum = c0+c1+c2;
  ps[t] = sum; __syncthreads();
  int xsc = sum;
  for (int off=1; off<256; off<<=1){
    int y = (t>=off)?ps[t-off]:0; __syncthreads();
    xsc += y; ps[t] = xsc; __syncthreads();
  }
  int ex = xsc - sum;
  int o0 = outbase + ex, o1 = o0 + c0, o2 = o1 + c1;
  offs[b*KPB + 3*t]   = o0;
  offs[b*KPB + 3*t+1] = o1;
  offs[b*KPB + 3*t+2] = o2;
  cur[3*t]   = (o0 - outbase) + hs;   // cursor past self slot
  cur[3*t+1] = (o1 - outbase) + hs;
  cur[3*t+2] = (o2 - outbase) + hs;
  __syncthreads();
  // pass A: place edges, compute unnormalized es, accumulate den
  for (int i=bs+t; i<be; i+=256){
    unsigned p = payload[i];
    int dl = (int)(p&255u), r = (int)((p>>8)&3u), s = (int)(p>>10);
    int lkey = dl*NREL + r;
    int pos = outbase + atomicAdd(&cur[lkey], 1);
    int d2 = b*DPB + dl;
    float4 a4 = ((const float4*)as_)[(size_t)r*N + s];
    float4 b4 = ((const float4*)ad_)[(size_t)r*N + d2];
    float ex0 = __expf(leaky(a4.x+b4.x));
    float ex1 = __expf(leaky(a4.y+b4.y));
    float ex2 = __expf(leaky(a4.z+b4.z));
    float ex3 = __expf(leaky(a4.w+b4.w));
    ssrc2[pos] = (unsigned)((r<<16) | s);
    alpha[pos] = (uint2){ h2pack(ex0,ex1), h2pack(ex2,ex3) };
    atomicAdd(&den[lkey*4+0], ex0); atomicAdd(&den[lkey*4+1], ex1);
    atomicAdd(&den[lkey*4+2], ex2); atomicAdd(&den[lkey*4+3], ex3);
  }
  __syncthreads();
  // self loops + normalization (thread t owns dst = b*DPB + t)
  if (dst < N){
    int starts[3] = {o0, o1, o2};
    #pragma unroll
    for (int r=0; r<NREL; r++){
      int lkey = 3*t + r;
      float4 a4 = ((const float4*)as_)[(size_t)r*N + dst];
      float4 b4 = ((const float4*)ad_)[(size_t)r*N + dst];
      float s0 = __expf(leaky(a4.x+b4.x));
      float s1 = __expf(leaky(a4.y+b4.y));
      float s2 = __expf(leaky(a4.z+b4.z));
      float s3 = __expf(leaky(a4.w+b4.w));
      float w = smw[r];
      float iv0 = w/(den[lkey*4+0]+s0);
      float iv1 = w/(den[lkey*4+1]+s1);
      float iv2 = w/(den[lkey*4+2]+s2);
      float iv3 = w/(den[lkey*4+3]+s3);
      int sp = starts[r];
      ssrc2[sp] = (unsigned)((r<<16) | dst);
      alpha[sp] = (uint2){ h2pack(s0*iv0, s1*iv1), h2pack(s2*iv2, s3*iv3) };
      int endp = outbase + cur[lkey];
      for (int j=sp+1; j<endp; ++j){
        uint2 v = alpha[j];
        union { unsigned u; __half h[2]; } p0, p1;
        p0.u = v.x; p1.u = v.y;
        alpha[j] = (uint2){ h2pack(__half2float(p0.h[0])*iv0, __half2float(p0.h[1])*iv1),
                            h2pack(__half2float(p1.h[0])*iv2, __half2float(p1.h[1])*iv3) };
      }
    }
  }
}

// --- aggregation: grid (8 channel-groups = XCD shard, dst-blocks); pure gather+FMA ---
__global__ __launch_bounds__(256) void k_segment(
    const int* __restrict__ offs, const unsigned* __restrict__ ssrc2,
    const __half* __restrict__ alpha, const unsigned* __restrict__ hq2,
    const float* __restrict__ biasMix, float* __restrict__ out, int N){
  const int cg   = blockIdx.x;            // channel group 0..7 -> XCD
  const int wave = threadIdx.x >> 6;
  const int lane = threadIdx.x & 63;
  const int eg = lane >> 2;               // 16 edge groups
  const int l4 = lane & 3;                // 4 lanes/edge, 4 ch each
  const int h  = cg >> 1;                 // head of this 16-ch group
  const unsigned* hb = hq2 + (size_t)cg*NREL*N*8;
  float4 bm = *(const float4*)(biasMix + cg*16 + l4*4);
  const int dst0 = blockIdx.y*8 + wave*2;

  #pragma unroll
  for (int dd=0; dd<2; ++dd){
    int dst = dst0 + dd;
    if (dst >= N) break;
    int beg = __builtin_amdgcn_readfirstlane(offs[dst*3]);
    int end = __builtin_amdgcn_readfirstlane(offs[dst*3+3]);
    float a0=0.f, a1=0.f, a2=0.f, a3=0.f;
    for (int i0=beg; i0<end; i0+=16){
      int i = i0 + eg;
      if (i < end){
        unsigned pk = ssrc2[i];
        float al = __half2float(alpha[(size_t)i*4 + h]);
        int s = (int)(pk & 0xFFFFu);
        int r = (int)(pk >> 16);
        uint2 u = *(const uint2*)(hb + ((size_t)(r*N + s)<<3) + (l4<<1));
        a0 = fmaf(al, __uint_as_float(u.x<<16),           a0);
        a1 = fmaf(al, __uint_as_float(u.x & 0xFFFF0000u), a1);
        a2 = fmaf(al, __uint_as_float(u.y<<16),           a2);
        a3 = fmaf(al, __uint_as_float(u.y & 0xFFFF0000u), a3);
      }
    }
    #pragma unroll
    for (int o=4; o<=32; o<<=1){
      a0 += __shfl_xor(a0, o); a1 += __shfl_xor(a1, o);
      a2 += __shfl_xor(a2, o); a3 += __shfl_xor(a3, o);
    }
    if (eg == 0){
      float4 o4 = {a0+bm.x, a1+bm.y, a2+bm.z, a3+bm.w};
      *(float4*)(out + (size_t)dst*OUT_DIM + cg*16 + l4*4) = o4;
    }
  }
}

extern "C" void kernel_launch(void* const* d_in, const int* in_sizes, int n_in,
                              void* d_out, int out_size, void* d_ws, size_t ws_size,
                              hipStream_t stream) {
  const float* x     = (const float*)d_in[0];
  const float* W     = (const float*)d_in[1];
  const float* att_s = (const float*)d_in[2];
  const float* att_d = (const float*)d_in[3];
  const float* bias  = (const float*)d_in[4];
  const float* rw    = (const float*)d_in[5];
  const int*   ei    = (const int*)d_in[6];
  const int*   et    = (const int*)d_in[7];
  float* out = (float*)d_out;

  const int N = in_sizes[0] / IN_DIM;
  const int E = in_sizes[7];
  const int M = NREL * N;
  const int NCHUNK = (E + CHUNK - 1) / CHUNK;
  const int NBUCK  = (N + DPB - 1) / DPB;
  const int NSLOT  = E + 3*N;

  char* ws = (char*)d_ws;
  size_t off = 0;
  auto alloc = [&](size_t bytes) -> void* {
    void* p = ws + off; off += (bytes + 255) & ~(size_t)255; return p;
  };
  unsigned* hq2     = (unsigned*)alloc((size_t)M * 64 * 4);       // [cg][r][node][8u32]
  float*    as_     = (float*)   alloc((size_t)M * 4 * 4);
  float*    ad_     = (float*)   alloc((size_t)M * 4 * 4);
  int*      offs    = (int*)     alloc(((size_t)NBUCK*KPB + 1) * 4);
  int*      histG   = (int*)     alloc((size_t)NBUCK * NCHUNK * 4);
  unsigned* payload = (unsigned*)alloc((size_t)E * 4);
  unsigned* ssrc2   = (unsigned*)alloc((size_t)NSLOT * 4);
  uint2*    alpha   = (uint2*)   alloc((size_t)NSLOT * 8);
  unsigned* xq      = (unsigned*)alloc((size_t)N * IN_DIM * 2);
  float*    smw     = (float*)   alloc(256);
  float*    biasMix = (float*)   alloc(512);
  u16*      WTall   = (u16*)     alloc((size_t)NREL * 144 * 128 * 2);

  k_prep<<<1, 128, 0, stream>>>(rw, bias, smw, biasMix);
  k_wprep<<<NREL, 256, 0, stream>>>(W, att_s, att_d, WTall);
  const int n8 = N * IN_DIM / 8;
  k_xq<<<(n8 + 255)/256, 256, 0, stream>>>(x, xq, n8);
  dim3 g1((N + 127) / 128, NREL);
  k_gemm<<<g1, 256, 0, stream>>>(xq, WTall, hq2, as_, ad_, N);
  k_hist<<<NCHUNK, 256, 0, stream>>>(ei, histG, E, NCHUNK, NBUCK);
  k_scanH<<<1, 256, 0, stream>>>(histG, NBUCK * NCHUNK);
  k_part<<<NCHUNK, 256, 0, stream>>>(et, ei, histG, payload, E, NCHUNK, NBUCK);
  k_csr<<<NBUCK, 256, 0, stream>>>(payload, histG, as_, ad_, smw, offs, ssrc2, alpha, E, N, NCHUNK, NBUCK);
  dim3 g2(8, (N + 7) / 8);
  k_segment<<<g2, 256, 0, stream>>>(offs, ssrc2, (const __half*)alpha, hq2, biasMix, out, N);
}

// Round 7
// 306.207 us; speedup vs baseline: 1.2607x; 1.2607x over previous
//
#include <hip/hip_runtime.h>
#include <hip/hip_bf16.h>
#include <hip/hip_fp16.h>
#include <math.h>

#define IN_DIM 128
#define OUT_DIM 128
#define HEADS 4
#define HEAD_DIM 32
#define NREL 3
#define NEG_SLOPE 0.2f

#define CHUNK 16384         // edges per partition chunk
#define BUCK_SHIFT 8
#define DPB 256             // dsts per bucket
#define KPB 768             // keys per bucket (DPB * NREL)
// assumes N <= 65536 (src fits 16 bits in packed words)

typedef __attribute__((ext_vector_type(8))) short short8;
typedef __attribute__((ext_vector_type(4))) float f32x4;
typedef unsigned short u16;

static __device__ __forceinline__ float leaky(float x){ return fmaxf(x, NEG_SLOPE*x); }
static __device__ __forceinline__ unsigned bf16rn(float x){
  unsigned b = __float_as_uint(x);
  b += 0x7FFF + ((b>>16)&1u);
  return b>>16;
}
static __device__ __forceinline__ unsigned h2pack(float a, float b){
  union { __half h[2]; unsigned u; } p;
  p.h[0] = __float2half_rn(a); p.h[1] = __float2half_rn(b);
  return p.u;
}

// --- relation softmax + mixed bias ---
__global__ void k_prep(const float* __restrict__ rw, const float* __restrict__ bias,
                       float* __restrict__ smw, float* __restrict__ biasMix){
  int t = threadIdx.x;
  float m = fmaxf(rw[0], fmaxf(rw[1], rw[2]));
  float e0=__expf(rw[0]-m), e1=__expf(rw[1]-m), e2=__expf(rw[2]-m);
  float inv = 1.f/(e0+e1+e2);
  if (t < 3) smw[t] = (t==0?e0:(t==1?e1:e2))*inv;
  if (t < 128)
    biasMix[t] = inv*(e0*bias[t] + e1*bias[OUT_DIM+t] + e2*bias[2*OUT_DIM+t]);
}

// --- x -> bf16 once ---
__global__ __launch_bounds__(256) void k_xq(const float* __restrict__ x,
                                            unsigned* __restrict__ xq, int n8){
  int i = blockIdx.x*256 + threadIdx.x;
  if (i >= n8) return;
  const float4* xp = (const float4*)x + (size_t)i*2;
  float4 v0 = xp[0], v1 = xp[1];
  uint4 o;
  o.x = bf16rn(v0.x) | (bf16rn(v0.y)<<16);
  o.y = bf16rn(v0.z) | (bf16rn(v0.w)<<16);
  o.z = bf16rn(v1.x) | (bf16rn(v1.y)<<16);
  o.w = bf16rn(v1.z) | (bf16rn(v1.w)<<16);
  ((uint4*)xq)[i] = o;
}

// --- build WTall[r][144][128] bf16: cols 0..127 = W^T, 128..135 = (W@att)^T, 136..143 = 0 ---
__global__ void k_wprep(const float* __restrict__ W, const float* __restrict__ att_s,
                        const float* __restrict__ att_d, u16* __restrict__ WTall){
  const int r = blockIdx.x;
  const int t = threadIdx.x;
  const float* Wr = W + (size_t)r*IN_DIM*OUT_DIM;
  u16* WT = WTall + (size_t)r*144*128;
  for (int i=t; i<128*128; i+=256){
    int k = i>>7, col = i&127;
    WT[col*128 + k] = (u16)bf16rn(Wr[i]);
  }
  if (t < 128){
    int k = t;
    for (int h=0; h<4; h++){
      float ss=0.f, sd=0.f;
      for (int c=0; c<32; c++){
        float w = Wr[k*128 + h*32 + c];
        ss = fmaf(w, att_s[(r*4+h)*32+c], ss);
        sd = fmaf(w, att_d[(r*4+h)*32+c], sd);
      }
      WT[(128+h)*128 + k] = (u16)bf16rn(ss);
      WT[(132+h)*128 + k] = (u16)bf16rn(sd);
    }
  }
  for (int i=t; i<8*128; i+=256) WT[136*128 + i] = 0;
}

// --- MFMA GEMM: h = x@W + fused a_s/a_d; h row-major: hq[(r*N+node)*64 u32] ---
__global__ __launch_bounds__(256) void k_gemm(
    const unsigned* __restrict__ xq, const u16* __restrict__ WTall,
    unsigned* __restrict__ hq, float* __restrict__ as_, float* __restrict__ ad_, int N){
  const int r = blockIdx.y;
  const int w = threadIdx.x >> 6;
  const int l = threadIdx.x & 63;
  const int row0 = blockIdx.x*128 + w*32;
  const int lg = l >> 4;
  const int lc = l & 15;

  const u16* WT = WTall + (size_t)r*144*128;
  const u16* xh = (const u16*)xq;

  f32x4 acc[2][9];
  #pragma unroll
  for (int rf=0; rf<2; rf++)
    #pragma unroll
    for (int cf=0; cf<9; cf++) acc[rf][cf] = (f32x4){0.f,0.f,0.f,0.f};

  for (int ks=0; ks<4; ks++){
    const int k0 = ks*32 + lg*8;
    short8 a[2];
    #pragma unroll
    for (int rf=0; rf<2; rf++){
      int row = row0 + rf*16 + lc;
      if (row < N) a[rf] = *(const short8*)(xh + (size_t)row*IN_DIM + k0);
      else         a[rf] = (short8){0,0,0,0,0,0,0,0};
    }
    #pragma unroll
    for (int cf=0; cf<9; cf++){
      short8 b = *(const short8*)(WT + (size_t)(cf*16 + lc)*128 + k0);
      #pragma unroll
      for (int rf=0; rf<2; rf++)
        acc[rf][cf] = __builtin_amdgcn_mfma_f32_16x16x32_bf16(a[rf], b, acc[rf][cf], 0, 0, 0);
    }
  }

  #pragma unroll
  for (int rf=0; rf<2; rf++){
    #pragma unroll
    for (int j=0; j<4; j++){
      int row = row0 + rf*16 + lg*4 + j;
      bool ok = (row < N);
      size_t nidx = (size_t)r*N + row;
      #pragma unroll
      for (int cf=0; cf<8; cf++){
        float v = acc[rf][cf][j];
        float pv = __shfl_xor(v, 1);
        if (ok && !(l&1))
          hq[nidx*64 + cf*8 + (lc>>1)] = bf16rn(v) | (bf16rn(pv)<<16);
      }
      float av = acc[rf][8][j];
      if (ok && lc < 4)       as_[nidx*4 + lc]     = av;
      else if (ok && lc < 8)  ad_[nidx*4 + (lc-4)] = av;
    }
  }
}

// --- pass 1: per-chunk histogram over dst buckets ---
__global__ __launch_bounds__(256) void k_hist(const int* __restrict__ ei,
                       int* __restrict__ histG, int E, int NCHUNK, int NBUCK){
  __shared__ int h[256];
  const int c = blockIdx.x, t = threadIdx.x;
  h[t] = 0; __syncthreads();
  const int* dstp = ei + E;
  const int base = c*CHUNK;
  #pragma unroll 4
  for (int it=0; it<CHUNK/256; ++it){
    int e = base + it*256 + t;
    if (e < E) atomicAdd(&h[dstp[e]>>BUCK_SHIFT], 1);
  }
  __syncthreads();
  if (t < NBUCK) histG[t*NCHUNK + c] = h[t];
}

// --- pass 2: exclusive scan of histG, in place; one block ---
__global__ __launch_bounds__(256) void k_scanH(int* __restrict__ histG, int T){
  __shared__ int ps[256];
  const int t = threadIdx.x;
  const int L = (T + 255)/256;
  const int base = t*L;
  int sum = 0;
  for (int i=0;i<L;i++){ int idx=base+i; if(idx<T) sum += histG[idx]; }
  ps[t] = sum; __syncthreads();
  int x = sum;
  for (int off=1; off<256; off<<=1){
    int y = (t>=off)?ps[t-off]:0; __syncthreads();
    x += y; ps[t] = x; __syncthreads();
  }
  int run = x - sum;
  for (int i=0;i<L;i++){
    int idx=base+i;
    if (idx<T){ int v = histG[idx]; histG[idx] = run; run += v; }
  }
}

// --- pass 3: partition edges into buckets; payload (src<<10 | rel<<8 | dstLocal) ---
__global__ __launch_bounds__(256) void k_part(const int* __restrict__ et, const int* __restrict__ ei,
                       const int* __restrict__ histG, unsigned* __restrict__ payload,
                       int E, int NCHUNK, int NBUCK){
  __shared__ int cur[256];
  const int c = blockIdx.x, t = threadIdx.x;
  if (t < NBUCK) cur[t] = histG[t*NCHUNK + c];
  __syncthreads();
  const int* dstp = ei + E;
  const int base = c*CHUNK;
  #pragma unroll 4
  for (int it=0; it<CHUNK/256; ++it){
    int e = base + it*256 + t;
    if (e < E){
      int d = dstp[e];
      int s = ei[e];
      int r = et[e];
      int b = d >> BUCK_SHIFT;
      int pos = atomicAdd(&cur[b], 1);
      payload[pos] = (unsigned)((d & (DPB-1)) | (r<<8) | (s<<10));
    }
  }
}

// --- pass 4: per-bucket CSR; self-loop slots; normalized smw-folded fp16 alpha ---
// ssrc2 word: src | r<<16 | dstLocal<<18
__global__ __launch_bounds__(256) void k_csr(const unsigned* __restrict__ payload,
                     const int* __restrict__ histG, const float* __restrict__ as_,
                     const float* __restrict__ ad_, const float* __restrict__ smw,
                     int* __restrict__ offs, unsigned* __restrict__ ssrc2,
                     uint2* __restrict__ alpha, int E, int N, int NCHUNK, int NBUCK){
  __shared__ int cntA[KPB];
  __shared__ int cur[KPB];
  __shared__ float den[KPB*4];
  __shared__ float ivs[KPB*4];
  __shared__ int ps[256];
  const int b = blockIdx.x, t = threadIdx.x;
  const int bs = histG[b*NCHUNK];
  const int be = (b+1 < NBUCK) ? histG[(b+1)*NCHUNK] : E;
  const int outbase = bs + 3*b*DPB;
  const int validD = min(N - b*DPB, DPB);

  for (int k=t; k<KPB; k+=256) cntA[k] = 0;
  for (int k=t; k<KPB*4; k+=256) den[k] = 0.f;
  __syncthreads();
  for (int i=bs+t; i<be; i+=256){
    unsigned p = payload[i];
    atomicAdd(&cntA[(int)(p&255u)*NREL + (int)((p>>8)&3u)], 1);
  }
  __syncthreads();
  const int dst = b*DPB + t;
  const int hs = (dst < N) ? 1 : 0;
  int c0 = cntA[3*t]   + hs;
  int c1 = cntA[3*t+1] + hs;
  int c2 = cntA[3*t+2] + hs;
  int sum = c0+c1+c2;
  ps[t] = sum; __syncthreads();
  int xsc = sum;
  for (int off=1; off<256; off<<=1){
    int y = (t>=off)?ps[t-off]:0; __syncthreads();
    xsc += y; ps[t] = xsc; __syncthreads();
  }
  int ex = xsc - sum;
  int o0 = outbase + ex, o1 = o0 + c0, o2 = o1 + c1;
  offs[b*KPB + 3*t]   = o0;
  offs[b*KPB + 3*t+1] = o1;
  offs[b*KPB + 3*t+2] = o2;
  cur[3*t]   = (o0 - outbase) + hs;   // cursor past self slot
  cur[3*t+1] = (o1 - outbase) + hs;
  cur[3*t+2] = (o2 - outbase) + hs;
  __syncthreads();
  // pass A: place edges, write raw exps, accumulate den
  for (int i=bs+t; i<be; i+=256){
    unsigned p = payload[i];
    int dl = (int)(p&255u), r = (int)((p>>8)&3u), s = (int)(p>>10);
    int lkey = dl*NREL + r;
    int pos = outbase + atomicAdd(&cur[lkey], 1);
    int d2 = b*DPB + dl;
    float4 a4 = ((const float4*)as_)[(size_t)r*N + s];
    float4 b4 = ((const float4*)ad_)[(size_t)r*N + d2];
    float ex0 = __expf(leaky(a4.x+b4.x));
    float ex1 = __expf(leaky(a4.y+b4.y));
    float ex2 = __expf(leaky(a4.z+b4.z));
    float ex3 = __expf(leaky(a4.w+b4.w));
    ssrc2[pos] = (unsigned)(s | (r<<16) | (dl<<18));
    alpha[pos] = (uint2){ h2pack(ex0,ex1), h2pack(ex2,ex3) };
    atomicAdd(&den[lkey*4+0], ex0); atomicAdd(&den[lkey*4+1], ex1);
    atomicAdd(&den[lkey*4+2], ex2); atomicAdd(&den[lkey*4+3], ex3);
  }
  __syncthreads();
  // self slots (raw exp) + iv table
  if (dst < N){
    int starts[3] = {o0, o1, o2};
    #pragma unroll
    for (int r=0; r<NREL; r++){
      int lkey = 3*t + r;
      float4 a4 = ((const float4*)as_)[(size_t)r*N + dst];
      float4 b4 = ((const float4*)ad_)[(size_t)r*N + dst];
      float s0 = __expf(leaky(a4.x+b4.x));
      float s1 = __expf(leaky(a4.y+b4.y));
      float s2 = __expf(leaky(a4.z+b4.z));
      float s3 = __expf(leaky(a4.w+b4.w));
      float w = smw[r];
      ivs[lkey*4+0] = w/(den[lkey*4+0]+s0);
      ivs[lkey*4+1] = w/(den[lkey*4+1]+s1);
      ivs[lkey*4+2] = w/(den[lkey*4+2]+s2);
      ivs[lkey*4+3] = w/(den[lkey*4+3]+s3);
      int sp = starts[r];
      ssrc2[sp] = (unsigned)(dst | (r<<16) | (t<<18));
      alpha[sp] = (uint2){ h2pack(s0,s1), h2pack(s2,s3) };
    }
  }
  __syncthreads();
  // parallel normalization sweep over the whole bucket window
  const int outend = outbase + (be - bs) + 3*validD;
  for (int i=outbase+t; i<outend; i+=256){
    unsigned p = ssrc2[i];
    int lkey = (int)(p>>18)*NREL + (int)((p>>16)&3u);
    float4 iv = *(const float4*)&ivs[lkey*4];
    uint2 v = alpha[i];
    union { unsigned u; __half h[2]; } p0, p1;
    p0.u = v.x; p1.u = v.y;
    alpha[i] = (uint2){ h2pack(__half2float(p0.h[0])*iv.x, __half2float(p0.h[1])*iv.y),
                        h2pack(__half2float(p1.h[0])*iv.z, __half2float(p1.h[1])*iv.w) };
  }
}

// --- aggregation: one wave per dst, flat slot loop, 8 slots in flight, pure gather+FMA ---
__global__ __launch_bounds__(256) void k_segment(
    const int* __restrict__ offs, const unsigned* __restrict__ ssrc2,
    const uint2* __restrict__ alpha, const unsigned* __restrict__ hq,
    const float* __restrict__ biasMix, float* __restrict__ out, int N){
  const int wave = threadIdx.x >> 6;
  const int lane = threadIdx.x & 63;
  const int dst  = blockIdx.x*4 + wave;
  if (dst >= N) return;
  const int g  = lane >> 3;   // slot group 0..7
  const int l8 = lane & 7;    // channel slot in group
  const int h0 = l8 >> 2;     // low-half head (0/1); high-half head = h0+2

  int beg = __builtin_amdgcn_readfirstlane(offs[dst*3]);
  int end = __builtin_amdgcn_readfirstlane(offs[dst*3+3]);

  float acc0[8], acc1[8];
  #pragma unroll
  for (int q=0; q<8; q++){ acc0[q]=0.f; acc1[q]=0.f; }

  for (int i0=beg; i0<end; i0+=8){
    int i = i0 + g;
    if (i < end){
      unsigned pk = ssrc2[i];
      uint2 av = alpha[i];
      int s = (int)(pk & 0xFFFFu);
      int r = (int)((pk >> 16) & 3u);
      union { unsigned u; __half h[2]; } pa, pb;
      pa.u = av.x; pb.u = av.y;
      float a0 = __half2float(pa.h[h0]);
      float a1 = __half2float(pb.h[h0]);
      const uint4* hp = (const uint4*)(hq + ((size_t)r*N + s)*64 + l8*4);
      uint4 u0 = hp[0];
      uint4 u1 = hp[8];
      const unsigned* p0 = (const unsigned*)&u0;
      const unsigned* p1 = (const unsigned*)&u1;
      #pragma unroll
      for (int q=0; q<4; q++){
        acc0[2*q]   = fmaf(a0, __uint_as_float(p0[q]<<16),           acc0[2*q]);
        acc0[2*q+1] = fmaf(a0, __uint_as_float(p0[q] & 0xFFFF0000u), acc0[2*q+1]);
        acc1[2*q]   = fmaf(a1, __uint_as_float(p1[q]<<16),           acc1[2*q]);
        acc1[2*q+1] = fmaf(a1, __uint_as_float(p1[q] & 0xFFFF0000u), acc1[2*q+1]);
      }
    }
  }

  #pragma unroll
  for (int o=8; o<=32; o<<=1){
    #pragma unroll
    for (int q=0; q<8; q++){
      acc0[q] += __shfl_xor(acc0[q], o);
      acc1[q] += __shfl_xor(acc1[q], o);
    }
  }

  if (g == 0){
    const float4* bmA = (const float4*)(biasMix + 8*l8);
    const float4* bmB = (const float4*)(biasMix + 64 + 8*l8);
    float4 x0 = bmA[0], x1 = bmA[1], y0 = bmB[0], y1 = bmB[1];
    float* orow = out + (size_t)dst*OUT_DIM;
    float4 o0 = {acc0[0]+x0.x, acc0[1]+x0.y, acc0[2]+x0.z, acc0[3]+x0.w};
    float4 o1 = {acc0[4]+x1.x, acc0[5]+x1.y, acc0[6]+x1.z, acc0[7]+x1.w};
    float4 o2 = {acc1[0]+y0.x, acc1[1]+y0.y, acc1[2]+y0.z, acc1[3]+y0.w};
    float4 o3 = {acc1[4]+y1.x, acc1[5]+y1.y, acc1[6]+y1.z, acc1[7]+y1.w};
    *(float4*)(orow + 8*l8)          = o0;
    *(float4*)(orow + 8*l8 + 4)      = o1;
    *(float4*)(orow + 64 + 8*l8)     = o2;
    *(float4*)(orow + 64 + 8*l8 + 4) = o3;
  }
}

extern "C" void kernel_launch(void* const* d_in, const int* in_sizes, int n_in,
                              void* d_out, int out_size, void* d_ws, size_t ws_size,
                              hipStream_t stream) {
  const float* x     = (const float*)d_in[0];
  const float* W     = (const float*)d_in[1];
  const float* att_s = (const float*)d_in[2];
  const float* att_d = (const float*)d_in[3];
  const float* bias  = (const float*)d_in[4];
  const float* rw    = (const float*)d_in[5];
  const int*   ei    = (const int*)d_in[6];
  const int*   et    = (const int*)d_in[7];
  float* out = (float*)d_out;

  const int N = in_sizes[0] / IN_DIM;
  const int E = in_sizes[7];
  const int M = NREL * N;
  const int NCHUNK = (E + CHUNK - 1) / CHUNK;
  const int NBUCK  = (N + DPB - 1) / DPB;
  const int NSLOT  = E + 3*N + 768;

  char* ws = (char*)d_ws;
  size_t off = 0;
  auto alloc = [&](size_t bytes) -> void* {
    void* p = ws + off; off += (bytes + 255) & ~(size_t)255; return p;
  };
  unsigned* hq      = (unsigned*)alloc((size_t)M * 64 * 4);       // [r][node][64u32]
  float*    as_     = (float*)   alloc((size_t)M * 4 * 4);
  float*    ad_     = (float*)   alloc((size_t)M * 4 * 4);
  int*      offs    = (int*)     alloc(((size_t)NBUCK*KPB + 1) * 4);
  int*      histG   = (int*)     alloc((size_t)NBUCK * NCHUNK * 4);
  unsigned* payload = (unsigned*)alloc((size_t)E * 4);
  unsigned* ssrc2   = (unsigned*)alloc((size_t)NSLOT * 4);
  uint2*    alpha   = (uint2*)   alloc((size_t)NSLOT * 8);
  unsigned* xq      = (unsigned*)alloc((size_t)N * IN_DIM * 2);
  float*    smw     = (float*)   alloc(256);
  float*    biasMix = (float*)   alloc(512);
  u16*      WTall   = (u16*)     alloc((size_t)NREL * 144 * 128 * 2);

  k_prep<<<1, 128, 0, stream>>>(rw, bias, smw, biasMix);
  k_wprep<<<NREL, 256, 0, stream>>>(W, att_s, att_d, WTall);
  const int n8 = N * IN_DIM / 8;
  k_xq<<<(n8 + 255)/256, 256, 0, stream>>>(x, xq, n8);
  dim3 g1((N + 127) / 128, NREL);
  k_gemm<<<g1, 256, 0, stream>>>(xq, WTall, hq, as_, ad_, N);
  k_hist<<<NCHUNK, 256, 0, stream>>>(ei, histG, E, NCHUNK, NBUCK);
  k_scanH<<<1, 256, 0, stream>>>(histG, NBUCK * NCHUNK);
  k_part<<<NCHUNK, 256, 0, stream>>>(et, ei, histG, payload, E, NCHUNK, NBUCK);
  k_csr<<<NBUCK, 256, 0, stream>>>(payload, histG, as_, ad_, smw, offs, ssrc2, alpha, E, N, NCHUNK, NBUCK);
  k_segment<<<(N + 3) / 4, 256, 0, stream>>>(offs, ssrc2, alpha, hq, biasMix, out, N);
}